// Round 12
// baseline (376.160 us; speedup 1.0000x reference)
//
#include <hip/hip_runtime.h>
#include <hip/hip_bf16.h>
#include <math.h>

// MultiheadAttention: B=4,S=2048,E=1024,H=16,DK=64, fp32 in/out.
// All-fp16 MFMA; static-max softmax in exp2 domain.
// GEMMs v6: LDS-BW analysis (R11): 64x64/wave tiles give 32 FLOP per
// LDS-byte -> ds_read 770cyc vs MFMA 621cyc per phase per CU -> MfmaUtil
// pinned at ~20-25% in ALL schedules (R2-R11). Fix is geometry: 256x256
// block, 8 waves, 128x64/wave (acc[8][4], 42.7 FLOP/B) -> LDS ~= MFMA.
// Double-buffered, R8-attn-proven schedule: stage(t+1)->compute->vmcnt(0)
// ->barrier (race-free by buffer parity, 4 rounds verified).
// launch_bounds(512,2) caps 256 regs (est ~216; kill-switch WRITE_SIZE).
// attn v9 (R11, passing): dbuf DMA + permlane P + ones-MFMA row sums.

typedef _Float16 f16x8 __attribute__((ext_vector_type(8)));
typedef _Float16 f16x4 __attribute__((ext_vector_type(4)));
typedef _Float16 f16x2 __attribute__((ext_vector_type(2)));
typedef float    f32x4 __attribute__((ext_vector_type(4)));
typedef unsigned int u32x2 __attribute__((ext_vector_type(2)));
typedef unsigned int u32x4 __attribute__((ext_vector_type(4)));

#define MFMA16(a,b,c) __builtin_amdgcn_mfma_f32_16x16x32_f16(a,b,c,0,0,0)

__device__ __forceinline__ void async_cp16(const _Float16* g, _Float16* l) {
    __builtin_amdgcn_global_load_lds(
        (const __attribute__((address_space(1))) unsigned int*)g,
        (__attribute__((address_space(3))) unsigned int*)l,
        16, 0, 0);
}

__device__ __forceinline__ f16x2 pk(float a, float b) {
    return __builtin_bit_cast(f16x2, __builtin_amdgcn_cvt_pkrtz(a, b));
}

// ---- merged prep: X fp32->fp16 (blocks 0..8191) and weight transpose+cvt
// W (K x N) -> WT fp16 (N x K) (blocks 8192..12287). Independent paths.
__global__ void __launch_bounds__(256) prep(
    const float* __restrict__ X,
    const float* __restrict__ Wq, const float* __restrict__ Wk,
    const float* __restrict__ Wv, const float* __restrict__ Wo,
    _Float16* __restrict__ Xh, _Float16* __restrict__ wt)
{
    __shared__ float tile[32][33];
    const int bx = blockIdx.x;
    if (bx < 8192) {
        int i = (bx*256 + threadIdx.x)*4;
        f32x4 x = *(const f32x4*)&X[i];
        f16x4 h;
        #pragma unroll
        for (int k=0;k<4;k++) h[k] = (_Float16)x[k];
        *(f16x4*)&Xh[i] = h;
        return;
    }
    int t = bx - 8192;               // 0..4095
    int mat = t >> 10;
    int tloc = t & 1023;
    const float* W = (mat==0)?Wq:(mat==1)?Wk:(mat==2)?Wv:Wo;
    _Float16* WT = wt + (size_t)mat*1048576;
    int kb = (tloc & 31) * 32;
    int nb = (tloc >> 5) * 32;
    int tx = threadIdx.x & 31, ty = threadIdx.x >> 5;   // ty 0..7
    #pragma unroll
    for (int r = 0; r < 4; ++r) {
        int row = ty + r*8;
        tile[row][tx] = W[(size_t)(kb+row)*1024 + nb + tx];
    }
    __syncthreads();
    #pragma unroll
    for (int r = 0; r < 4; ++r) {
        int row = ty + r*8;
        WT[(size_t)(nb+row)*1024 + kb + tx] = (_Float16)tile[tx][row];
    }
}

// ---- 256x64 tile staging: 4 rounds x 512 threads x 16B. Linear dest;
// source granule pre-swizzled (d&7)^(row&7) so fragment reads at
// lds[row*64 + (g^(row&7))*8] are conflict-free (measured 0, R5-R11).
__device__ __forceinline__ void stage256(
    const _Float16* __restrict__ g, _Float16* l, int tid)
{
    #pragma unroll
    for (int j = 0; j < 4; ++j) {
        int d   = j*512 + tid;
        int row = d >> 3;
        int sg  = (d & 7) ^ (row & 7);
        async_cp16(&g[(size_t)row*1024 + sg*8], l + d*8);
    }
}

// K-loop: 16 tiles, double-buffered. Iter t: stage tile t+1 into buf^1,
// compute both ks-phases from buf, vmcnt(0) + one barrier. Overwrite of a
// buffer is a full barrier after its last reader in every wave's program
// order (R8-proven skeleton). acc[8][4] = 128x64 output per wave.
#define GEMM_K_LOOP_256()                                                      \
    stage256(Ag, &sA[0][0], tid);                                              \
    stage256(Bg, &sB[0][0], tid);                                              \
    asm volatile("s_waitcnt vmcnt(0)" ::: "memory");                           \
    __builtin_amdgcn_s_barrier();                                              \
    __builtin_amdgcn_sched_barrier(0);                                         \
    {                                                                          \
        const _Float16* AgN = Ag + 64;                                         \
        const _Float16* BgN = Bg + 64;                                         \
        const int abase0 = (wr*128 + cc)*64 + ((q4    ^(cc&7))*8);             \
        const int abase1 = (wr*128 + cc)*64 + (((4+q4)^(cc&7))*8);             \
        const int bbase0 = (wc*64  + cc)*64 + ((q4    ^(cc&7))*8);             \
        const int bbase1 = (wc*64  + cc)*64 + (((4+q4)^(cc&7))*8);             \
        _Pragma("unroll 2")                                                    \
        for (int t = 0; t < 16; ++t) {                                         \
            const int cur = t & 1;                                             \
            const _Float16* ka = &sA[cur][0];                                  \
            const _Float16* kb_ = &sB[cur][0];                                 \
            if (t < 15) {                                                      \
                stage256(AgN, &sA[cur^1][0], tid);                             \
                stage256(BgN, &sB[cur^1][0], tid);                             \
            }                                                                  \
            f16x8 af[8], bf[4];                                                \
            _Pragma("unroll")                                                  \
            for (int i = 0; i < 8; ++i)                                        \
                af[i] = *(const f16x8*)&ka[abase0 + i*1024];                   \
            _Pragma("unroll")                                                  \
            for (int j = 0; j < 4; ++j)                                        \
                bf[j] = *(const f16x8*)&kb_[bbase0 + j*1024];                  \
            __builtin_amdgcn_s_setprio(1);                                     \
            _Pragma("unroll")                                                  \
            for (int i = 0; i < 8; ++i)                                        \
                _Pragma("unroll")                                              \
                for (int j = 0; j < 4; ++j)                                    \
                    acc[i][j] = MFMA16(af[i], bf[j], acc[i][j]);               \
            __builtin_amdgcn_s_setprio(0);                                     \
            _Pragma("unroll")                                                  \
            for (int i = 0; i < 8; ++i)                                        \
                af[i] = *(const f16x8*)&ka[abase1 + i*1024];                   \
            _Pragma("unroll")                                                  \
            for (int j = 0; j < 4; ++j)                                        \
                bf[j] = *(const f16x8*)&kb_[bbase1 + j*1024];                  \
            __builtin_amdgcn_s_setprio(1);                                     \
            _Pragma("unroll")                                                  \
            for (int i = 0; i < 8; ++i)                                        \
                _Pragma("unroll")                                              \
                for (int j = 0; j < 4; ++j)                                    \
                    acc[i][j] = MFMA16(af[i], bf[j], acc[i][j]);               \
            __builtin_amdgcn_s_setprio(0);                                     \
            AgN += 64; BgN += 64;                                              \
            asm volatile("s_waitcnt vmcnt(0)" ::: "memory");                   \
            __builtin_amdgcn_s_barrier();                                      \
            __builtin_amdgcn_sched_barrier(0);                                 \
        }                                                                      \
    }

// ---- fused QKV projection GEMM: C = X * W^T + b, 256x256 tile ----
// grid 384: xcd = id&7; per-XCD lid (0..47) walks nb-major (nb:12)(m:4)
// so the 4 m-consumers of each 512KB B-panel are adjacent; the XCD's
// 4 A-panels (2MB) stay L2-hot.
__global__ void __launch_bounds__(512,2) gemm_qkv(
    const _Float16* __restrict__ Xh, const _Float16* __restrict__ wt,
    const float* __restrict__ bq, const float* __restrict__ bk, const float* __restrict__ bv,
    _Float16* __restrict__ Q, _Float16* __restrict__ K, _Float16* __restrict__ Vt)
{
    __shared__ __align__(16) _Float16 sA[2][16384];   // 2 x 256x64
    __shared__ __align__(16) _Float16 sB[2][16384];

    const int id = blockIdx.x;        // 0..383
    const int xcd = id & 7;
    const int lid = id >> 3;          // 0..47
    const int nblk = lid >> 2;        // 0..11
    const int m_lo = lid & 3;         // 0..3
    const int mblk = m_lo*8 + xcd;    // 0..31

    const int tid = threadIdx.x;
    const int wave = tid >> 6, lane = tid & 63;
    const int wr = wave >> 2, wc = wave & 3;   // 2M x 4N, 128x64/wave
    const int q4 = lane >> 4, cc = lane & 15;

    const int mat = nblk >> 2;                // 0=q 1=k 2=v
    const int colbase = (nblk & 3) * 256;
    const _Float16* Bg = wt + (size_t)mat*1048576 + (size_t)colbase*1024;
    const _Float16* Ag = Xh + (size_t)mblk*262144;

    f32x4 acc[8][4] = {};

    GEMM_K_LOOP_256()

    const float* bias = (mat==0)?bq:(mat==1)?bk:bv;
    const float QSCALE = 0.125f * 1.44269504f;
    #pragma unroll
    for (int i=0;i<8;i++)
      #pragma unroll
      for (int j=0;j<4;j++)
        #pragma unroll
        for (int r=0;r<4;r++){
            int m = mblk*256 + wr*128 + i*16 + q4*4 + r;
            int ncol = colbase + wc*64 + j*16 + cc;     // 0..1023 in matrix
            float val = acc[i][j][r] + bias[ncol];
            int b = m >> 11, s = m & 2047;
            int h = ncol >> 6, dk = ncol & 63;
            if (mat == 2) {
                Vt[((size_t)(b*16+h)*64 + dk)*2048 + s] = (_Float16)val;  // V^T: (B,H,DK,S)
            } else {
                size_t qi = ((size_t)(b*16+h)*2048 + s)*64 + dk;          // (B,H,S,DK)
                if (mat == 0) Q[qi] = (_Float16)(val * QSCALE);
                else          K[qi] = (_Float16)val;
            }
        }
}

// ---- output projection: out = ctx * Wo^T + bo, 256x256 tile ----
// grid 128 (one round, 4m x 4n per XCD: 2MB A + 2MB B fits L2).
__global__ void __launch_bounds__(512,2) gemm_out(
    const _Float16* __restrict__ Ctx, const _Float16* __restrict__ wt,
    const float* __restrict__ bo,
    float* __restrict__ out)
{
    __shared__ __align__(16) _Float16 sA[2][16384];
    __shared__ __align__(16) _Float16 sB[2][16384];

    const int id = blockIdx.x;        // 0..127
    const int xcd = id & 7;
    const int lid = id >> 3;          // 0..15
    const int nblk = lid >> 2;        // 0..3
    const int m_lo = lid & 3;         // 0..3
    const int mblk = m_lo*8 + xcd;    // 0..31

    const int tid = threadIdx.x;
    const int wave = tid >> 6, lane = tid & 63;
    const int wr = wave >> 2, wc = wave & 3;
    const int q4 = lane >> 4, cc = lane & 15;

    const _Float16* Bg = wt + (size_t)3*1048576 + (size_t)nblk*256*1024;
    const _Float16* Ag = Ctx + (size_t)mblk*262144;

    f32x4 acc[8][4] = {};

    GEMM_K_LOOP_256()

    #pragma unroll
    for (int i=0;i<8;i++)
      #pragma unroll
      for (int j=0;j<4;j++)
        #pragma unroll
        for (int r=0;r<4;r++){
            int m = mblk*256 + wr*128 + i*16 + q4*4 + r;
            int n = nblk*256 + wc*64 + j*16 + cc;
            out[(size_t)m*1024 + n] = acc[i][j][r] + bo[n];
        }
}

// ---- flash attention, static-max softmax: 128 q-rows/block, 64-key tiles ----
// 1-D grid 1024: XCD = id%8; 4 blocks/CU = one exact resident round.
// Double-buffered K/V tiles via global_load_lds with source-granule XOR
// swizzle; per tile: issue next-tile DMA -> compute -> vmcnt(0) -> barrier.
// Row sums via ones-MFMA (oL, same C layout as o -> inv = 1/oL[m][r]).
__global__ void __launch_bounds__(256,4) attn(
    const _Float16* __restrict__ Qg, const _Float16* __restrict__ Kg,
    const _Float16* __restrict__ Vg,
    _Float16* __restrict__ Ctx)
{
    __shared__ __align__(16) _Float16 sK[2][4096];   // 64 keys x 64 dims
    __shared__ __align__(16) _Float16 sV[2][4096];   // 64 dims x 64 keys

    const int id = blockIdx.x;
    const int xcd = id & 7;
    const int t2 = id >> 3;           // 0..127
    const int qc = t2 & 15;
    const int bh = (t2 >> 4) * 8 + xcd;

    const int tid = threadIdx.x;
    const int wave = tid >> 6, lane = tid & 63;
    const int q4 = lane >> 4, cc = lane & 15;

    const size_t hoff = (size_t)bh * 131072;   // 2048*64
    const _Float16* Qp = Qg + hoff;
    const _Float16* Kp = Kg + hoff;
    const _Float16* Vp = Vg + hoff;

    const int qbase = qc*128 + wave*32;

    f16x8 qf[2][2];
    #pragma unroll
    for (int m=0;m<2;m++)
      #pragma unroll
      for (int ks=0;ks<2;ks++)
        qf[m][ks] = *(const f16x8*)&Qp[(qbase+m*16+cc)*64 + ks*32 + q4*8];

    f16x8 vones;
    #pragma unroll
    for (int k=0;k<8;k++) vones[k] = (_Float16)1.0f;

    f32x4 o[2][4] = {};
    f32x4 oL[2] = {};   // row sums via ones-MFMA, same layout as o

    // ---- precomputed loop-invariant offsets (element units) ----
    const int srow = tid >> 3;
    const int scg  = ((tid & 7) ^ ((tid >> 3) & 7)) * 8;
    int kofs[2], vofs[2], dofs[2];
    #pragma unroll
    for (int rr = 0; rr < 2; ++rr) {
        kofs[rr] = (rr*32 + srow)*64 + scg;
        vofs[rr] = (rr*32 + srow)*2048 + scg;
        dofs[rr] = rr*2048 + wave*512;
    }
    int okA[4], okB[4];
    #pragma unroll
    for (int kj=0;kj<4;kj++){
        okA[kj] = (kj*16+cc)*64 + ((q4    ^(cc&7))*8);
        okB[kj] = (kj*16+cc)*64 + (((4+q4)^(cc&7))*8);
    }
    int ov[2][4];
    #pragma unroll
    for (int ks=0;ks<2;ks++)
      #pragma unroll
      for (int v=0;v<4;v++)
        ov[ks][v] = (v*16+cc)*64 + (((ks*4+q4)^(cc&7))*8);

    // prologue: stage tile 0 into buffer 0
    #pragma unroll
    for (int rr = 0; rr < 2; ++rr) {
        async_cp16(Kp + kofs[rr], &sK[0][dofs[rr]]);
        async_cp16(Vp + vofs[rr], &sV[0][dofs[rr]]);
    }
    asm volatile("s_waitcnt vmcnt(0)" ::: "memory");
    __syncthreads();
    __builtin_amdgcn_sched_barrier(0);

    const _Float16* KbN = Kp + 4096;   // next-tile bases, strength-reduced
    const _Float16* VbN = Vp + 64;

    #pragma unroll 2
    for (int kt = 0; kt < 32; ++kt) {
        const int cur = kt & 1;
        const _Float16* kc = &sK[cur][0];
        const _Float16* vc = &sV[cur][0];

        // issue next tile's DMA into the OTHER buffer (hidden under compute)
        if (kt < 31) {
            _Float16* kn = &sK[cur ^ 1][0];
            _Float16* vn = &sV[cur ^ 1][0];
            #pragma unroll
            for (int rr = 0; rr < 2; ++rr) {
                async_cp16(KbN + kofs[rr], kn + dofs[rr]);
                async_cp16(VbN + vofs[rr], vn + dofs[rr]);
            }
        }

        // compute on current tile: per k-slice ks (32 keys), kj pair -> QK^T
        // -> exp2 -> pack -> permlane exchange -> PV + ones-MFMA row sum.
        #pragma unroll
        for (int ks=0;ks<2;ks++){
            unsigned Ud[2][2], Wd[2][2];   // [m][dword]; U: kj=2ks, W: kj=2ks+1
            #pragma unroll
            for (int aa=0;aa<2;aa++){
                int kj = ks*2 + aa;
                f16x8 k0 = *(const f16x8*)&kc[okA[kj]];
                f16x8 k1 = *(const f16x8*)&kc[okB[kj]];
                #pragma unroll
                for (int m=0;m<2;m++){
                    f32x4 z = {};
                    f32x4 s = MFMA16(k0, qf[m][0], z);
                    s = MFMA16(k1, qf[m][1], s);
                    float p0 = __builtin_amdgcn_exp2f(s[0]);
                    float p1 = __builtin_amdgcn_exp2f(s[1]);
                    float p2 = __builtin_amdgcn_exp2f(s[2]);
                    float p3 = __builtin_amdgcn_exp2f(s[3]);
                    unsigned d0 = __builtin_bit_cast(unsigned, pk(p0, p1));
                    unsigned d1 = __builtin_bit_cast(unsigned, pk(p2, p3));
                    if (aa == 0) { Ud[m][0] = d0; Ud[m][1] = d1; }
                    else         { Wd[m][0] = d0; Wd[m][1] = d1; }
                }
            }
            // A-frag: lane (cc,q4) needs keys 32ks+8q4+{0..7} of q-row cc.
            f16x8 pa[2];
            #pragma unroll
            for (int m=0;m<2;m++){
                u32x2 x0 = __builtin_amdgcn_permlane32_swap(Ud[m][0], Wd[m][0], false, false);
                u32x2 r02 = __builtin_amdgcn_permlane16_swap(x0[0], x0[1], false, false);
                u32x2 x1 = __builtin_amdgcn_permlane32_swap(Ud[m][1], Wd[m][1], false, false);
                u32x2 r13 = __builtin_amdgcn_permlane16_swap(x1[0], x1[1], false, false);
                u32x4 pw;
                pw[0] = r02[0]; pw[1] = r13[0]; pw[2] = r02[1]; pw[3] = r13[1];
                pa[m] = __builtin_bit_cast(f16x8, pw);
            }
            #pragma unroll
            for (int v=0;v<4;v++){
                f16x8 vf = *(const f16x8*)&vc[ov[ks][v]];
                o[0][v] = MFMA16(pa[0], vf, o[0][v]);
                o[1][v] = MFMA16(pa[1], vf, o[1][v]);
            }
            oL[0] = MFMA16(pa[0], vones, oL[0]);
            oL[1] = MFMA16(pa[1], vones, oL[1]);
        }

        KbN += 4096;
        VbN += 64;
        asm volatile("s_waitcnt vmcnt(0)" ::: "memory");
        __syncthreads();   // next tile staged + all reads of cur done
        __builtin_amdgcn_sched_barrier(0);
    }

    int b = bh >> 4, h = bh & 15;
    #pragma unroll
    for (int m=0;m<2;m++)
      #pragma unroll
      for (int r=0;r<4;r++){
        float inv = 1.f / oL[m][r];
        int s = qbase + m*16 + q4*4 + r;
        #pragma unroll
        for (int v=0;v<4;v++){
            float val = o[m][v][r]*inv;
            int dk = v*16 + cc;
            Ctx[((size_t)(b*2048+s)*16 + h)*64 + dk] = (_Float16)val;  // (B,S,H,DK)
        }
      }
}

extern "C" void kernel_launch(void* const* d_in, const int* in_sizes, int n_in,
                              void* d_out, int out_size, void* d_ws, size_t ws_size,
                              hipStream_t stream)
{
    const float* q  = (const float*)d_in[0];
    const float* Wq = (const float*)d_in[1];
    const float* bq = (const float*)d_in[2];
    const float* Wk = (const float*)d_in[3];
    const float* bk = (const float*)d_in[4];
    const float* Wv = (const float*)d_in[5];
    const float* bv = (const float*)d_in[6];
    const float* Wo = (const float*)d_in[7];
    const float* bo = (const float*)d_in[8];
    float* out = (float*)d_out;

    _Float16* ws  = (_Float16*)d_ws;
    _Float16* wt  = ws;                   // 4 x 1M fp16 = 8MB
    _Float16* Xh  = ws + 4194304;         // 16MB
    _Float16* Q   = ws + 12582912;
    _Float16* K   = ws + 20971520;
    _Float16* Vt  = ws + 29360128;        // end 37748736 el = 75.5MB
    _Float16* Ctx = Xh;                   // X dead after gemm_qkv

    prep<<<dim3(12288), 256, 0, stream>>>(q, Wq, Wk, Wv, Wo, Xh, wt);
    gemm_qkv<<<dim3(384), 512, 0, stream>>>(Xh, wt, bq, bk, bv, Q, K, Vt);
    attn<<<dim3(1024), 256, 0, stream>>>(Q, K, Vt, Ctx);
    gemm_out<<<dim3(128), 512, 0, stream>>>(Ctx, wt, bo, out);
}